// Round 17
// baseline (213.520 us; speedup 1.0000x reference)
//
#include <hip/hip_runtime.h>
#include <math.h>

typedef _Float16 half4 __attribute__((ext_vector_type(4)));
typedef float f32x4 __attribute__((ext_vector_type(4)));

#define MFMA16 __builtin_amdgcn_mfma_f32_16x16x16f16

constexpr int WS = 7, HH = 56, HW = 3136;

// d_ws layout: fp16 tiles then f32 folded biases
constexpr int QKVP_OFF  = 0;       // 27648 fp16 (18nt x 6kt x 256)
constexpr int PROJP_OFF = 27648;   // 9216 (6x6x256)
constexpr int W1P_OFF   = 36864;   // 9216
constexpr int W2P_OFF   = 46080;   // 9216
constexpr int BIASF_BYTE = 110592; // f32 [288 qkv' | 96 mlp1']

// LDS: R1 [64 tok][100 fp16] = 12800 B (XLN -> K, token-major blocks)
//      R2 [96 d][72 fp16]    = 13824 B (V, d-major)
constexpr int R2_BYTE = 12800;
constexpr int SMEM_BYTES = 12800 + 13824;   // 26624 -> 6 blocks/CU by LDS

__device__ __forceinline__ int labD(int v) { return v < 49 ? 0 : (v < 53 ? 1 : 2); }
__device__ __forceinline__ int div7d(int v) { return (v * 9363) >> 16; }  // valid 0..63

__device__ __forceinline__ half4 pk4(f32x4 v) {
    half4 r;
    r[0] = (_Float16)v[0]; r[1] = (_Float16)v[1];
    r[2] = (_Float16)v[2]; r[3] = (_Float16)v[3];
    return r;
}

// ---------------------------------------------------------------------------
// Weight pre-pack, K=16 A-fragment layout [nt][kt][l4][l15][j]:
//   elem = W[k = kt*16+l4*4+j][n = nt*16+l15]  (row-scaled by LN gamma where
//   applicable).  biasf = folded LN beta contributions (unchanged).
// ---------------------------------------------------------------------------
__global__ __launch_bounds__(256) void pack_wE(
    const float* __restrict__ qkv_w, const float* __restrict__ proj_w,
    const float* __restrict__ w1, const float* __restrict__ w2,
    const float* __restrict__ ln1_g, const float* __restrict__ ln1_b,
    const float* __restrict__ ln2_g, const float* __restrict__ ln2_b,
    const float* __restrict__ qkv_b, const float* __restrict__ mlp_b1,
    _Float16* __restrict__ ws, float* __restrict__ bias_out)
{
    int blk = blockIdx.x;
    if (blk < 216) {
        int i = blk * 256 + threadIdx.x;
        const float* src; int ncol, local; const float* gv = nullptr;
        if (i < 27648)      { src = qkv_w;  ncol = 288; local = i; gv = ln1_g; }
        else if (i < 36864) { src = proj_w; ncol = 96;  local = i - 27648; }
        else if (i < 46080) { src = w1;     ncol = 96;  local = i - 36864; gv = ln2_g; }
        else                { src = w2;     ncol = 96;  local = i - 46080; }
        int j   = local & 3;
        int l15 = (local >> 2) & 15;
        int l4  = (local >> 6) & 3;
        int rest = local >> 8;
        int kt = rest % 6, nt = rest / 6;
        int k = kt * 16 + l4 * 4 + j, n = nt * 16 + l15;
        float v = src[k * ncol + n];
        if (gv) v *= gv[k];
        ws[i] = (_Float16)v;
    } else if (blk == 216) {
        int n = threadIdx.x;
        float s = qkv_b[n];
        for (int k = 0; k < 96; ++k) s += ln1_b[k] * qkv_w[k * 288 + n];
        bias_out[n] = s;
    } else {
        int t = threadIdx.x;
        if (t < 32) {
            int n = 256 + t;
            float s = qkv_b[n];
            for (int k = 0; k < 96; ++k) s += ln1_b[k] * qkv_w[k * 288 + n];
            bias_out[n] = s;
        } else if (t < 128) {
            int n = t - 32;
            float s = mlp_b1[n];
            for (int k = 0; k < 96; ++k) s += ln2_b[k] * w1[k * 96 + n];
            bias_out[288 + n] = s;
        }
    }
}

// ---------------------------------------------------------------------------
// Fully fused Swin block, K=16 MFMA everywhere.  D granule (4ch) == B granule
// (4ch), so Q/P/O/XT/YT pass GEMM->GEMM in REGISTERS.  LDS only for K (cross-
// token A-operand of scores) and V (cross-token A-operand of PV).
// ONE barrier: K/V publish.  26.6 KB LDS.
// ---------------------------------------------------------------------------
__global__ __launch_bounds__(256, 5) void attn_kE(
    const float* __restrict__ x,
    const float* __restrict__ attn_bias,
    const float* __restrict__ proj_b,
    const float* __restrict__ mlp_b2,
    const _Float16* __restrict__ wpack,
    const float* __restrict__ biasf,
    float* __restrict__ out)
{
    __shared__ __align__(16) char smem[SMEM_BYTES];
    _Float16* R1 = (_Float16*)smem;
    _Float16* R2 = (_Float16*)(smem + R2_BYTE);

    const _Float16* qkvp  = wpack + QKVP_OFF;
    const _Float16* projp = wpack + PROJP_OFF;
    const _Float16* w1p   = wpack + W1P_OFF;
    const _Float16* w2p   = wpack + W2P_OFF;

    const int blk = blockIdx.x;
    const int b   = blk >> 6;
    const int w   = blk & 63;
    const int wh  = w >> 3, ww = w & 7;
    const int tid = threadIdx.x;
    const int wv  = tid >> 6, lane = tid & 63;
    const int l15 = lane & 15, l4 = lane >> 4;

    const int  tcol   = wv * 16 + l15;     // this thread's token (D column)
    const bool tok_ok = tcol < 49;

    // ---- wave 3 zeroes V pad cols 48..63 (before its own col-48 store) ----
    if (wv == 3) {
        #pragma unroll
        for (int i = 0; i < 3; ++i) {
            int idx = i * 64 + lane;           // 192 uint4 = 96 d x 32 B
            int d = idx >> 1, half = idx & 1;
            *(uint4*)&R2[d * 72 + 48 + half * 8] = make_uint4(0, 0, 0, 0);
        }
    }

    // ---- gather window (rolled) into registers: 4 threads/token ----------
    const int t_own = tid >> 2, part = tid & 3;
    const bool active = (tid < 196);
    float4 xq[6];
    float m = 0.f, rinv = 0.f;
    if (active) {
        int i = div7d(t_own), j = t_own - i * 7;
        int row = wh * WS + i + 3; if (row >= HH) row -= HH;
        int col = ww * WS + j + 3; if (col >= HH) col -= HH;
        const float* xp = &x[(((size_t)b * HW + row * HH + col) * 96) + part * 24];
        #pragma unroll
        for (int q = 0; q < 6; ++q) xq[q] = *(const float4*)&xp[q * 4];
        float sum = 0.f, sq = 0.f;
        #pragma unroll
        for (int q = 0; q < 6; ++q) {
            sum += xq[q].x + xq[q].y + xq[q].z + xq[q].w;
            sq  += xq[q].x * xq[q].x + xq[q].y * xq[q].y
                 + xq[q].z * xq[q].z + xq[q].w * xq[q].w;
        }
        sum += __shfl_xor(sum, 1); sq += __shfl_xor(sq, 1);
        sum += __shfl_xor(sum, 2); sq += __shfl_xor(sq, 2);
        m = sum * (1.0f / 96.0f);
        rinv = rsqrtf(sq * (1.0f / 96.0f) - m * m + 1e-5f);
    }

    // ---- normalize -> XLN token-major blocks (own-wave tokens) ------------
    if (active) {
        #pragma unroll
        for (int g = 0; g < 6; ++g) {
            half4 st;
            st[0] = (_Float16)((xq[g].x - m) * rinv);
            st[1] = (_Float16)((xq[g].y - m) * rinv);
            st[2] = (_Float16)((xq[g].z - m) * rinv);
            st[3] = (_Float16)((xq[g].w - m) * rinv);
            *(half4*)&R1[t_own * 100 + part * 24 + g * 4] = st;
        }
    }
    // NO barrier: QKV B-frags below read own token's block, written by own
    // wave (gather lanes 4*l15+part belong to wave wv).

    // ---- QKV GEMM (K=16): B = XLN own-token frags; D -> Q regs / K,V LDS --
    half4 q2[6];
    {
        half4 bx[6];
        #pragma unroll
        for (int kt = 0; kt < 6; ++kt)
            bx[kt] = *(half4*)&R1[tcol * 100 + kt * 16 + l4 * 4];

        // Q: nt 0..5 -> registers (pad-token cols garbage, masked in softmax)
        #pragma unroll
        for (int nt = 0; nt < 6; ++nt) {
            f32x4 acc = {0.f, 0.f, 0.f, 0.f};
            #pragma unroll
            for (int kt = 0; kt < 6; ++kt) {
                half4 a = *(const half4*)&qkvp[((nt * 6 + kt) * 4 + l4) * 64 + l15 * 4];
                acc = MFMA16(a, bx[kt], acc, 0, 0, 0);
            }
            int n0 = nt * 16 + l4 * 4;
            f32x4 b4 = *(const f32x4*)&biasf[n0];
            q2[nt] = pk4(acc + b4);
        }
        // K: nt 6..11 -> overwrite own token block in R1 (channel-disjoint
        // by l4 vs any remaining XLN reads; in-order within thread)
        #pragma unroll
        for (int nt = 6; nt < 12; ++nt) {
            f32x4 acc = {0.f, 0.f, 0.f, 0.f};
            #pragma unroll
            for (int kt = 0; kt < 6; ++kt) {
                half4 a = *(const half4*)&qkvp[((nt * 6 + kt) * 4 + l4) * 64 + l15 * 4];
                acc = MFMA16(a, bx[kt], acc, 0, 0, 0);
            }
            int n0 = nt * 16 + l4 * 4;
            f32x4 b4 = *(const f32x4*)&biasf[n0];
            *(half4*)&R1[tcol * 100 + (n0 - 96)] = pk4(acc + b4);
        }
        // V: nt 12..17 -> write-scatter to R2 [d][72] (guarded; pads stay 0)
        #pragma unroll
        for (int nt = 12; nt < 18; ++nt) {
            f32x4 acc = {0.f, 0.f, 0.f, 0.f};
            #pragma unroll
            for (int kt = 0; kt < 6; ++kt) {
                half4 a = *(const half4*)&qkvp[((nt * 6 + kt) * 4 + l4) * 64 + l15 * 4];
                acc = MFMA16(a, bx[kt], acc, 0, 0, 0);
            }
            int n0 = nt * 16 + l4 * 4;
            f32x4 b4 = *(const f32x4*)&biasf[n0];
            int vd0 = n0 - 192;
            if (tok_ok) {
                #pragma unroll
                for (int r = 0; r < 4; ++r)
                    R2[(vd0 + r) * 72 + tcol] = (_Float16)(acc[r] + b4[r]);
            }
        }
    }
    __syncthreads();   // B2: K and V published (the ONLY barrier)
    __builtin_amdgcn_s_setprio(1);

    // ---- shift-mask tables (k = knt*16 + l4*4 + r, q = tcol uniform) ------
    const bool qo = tok_ok;
    const int qcl = qo ? tcol : 48;
    bool keep[4][4]; int kcl[4][4];
    {
        int qi = div7d(qcl), qj = qcl - qi * 7;
        int lqr = labD(wh * WS + qi), lqc = labD(ww * WS + qj);
        #pragma unroll
        for (int knt = 0; knt < 4; ++knt) {
            #pragma unroll
            for (int r = 0; r < 4; ++r) {
                int k = knt * 16 + l4 * 4 + r;
                int kc = k < 49 ? k : 48;
                kcl[knt][r] = kc;
                int ki = div7d(kc), kj = kc - ki * 7;
                keep[knt][r] = qo && (k < 49) &&
                               (lqr == labD(wh * WS + ki)) &&
                               (lqc == labD(ww * WS + kj));
            }
        }
    }

    // ---- per-head: scores (K=16) -> softmax (regs) -> PV (K=16) -----------
    const float scale = 0.17677669529663687f;
    half4 o2[6];
    #pragma unroll
    for (int h = 0; h < 3; ++h) {
        f32x4 sh[4];
        #pragma unroll
        for (int knt = 0; knt < 4; ++knt) {
            f32x4 acc = {0.f, 0.f, 0.f, 0.f};
            #pragma unroll
            for (int dt = 0; dt < 2; ++dt) {
                half4 kf = *(half4*)&R1[(knt * 16 + l15) * 100 + h * 32 + dt * 16 + l4 * 4];
                acc = MFMA16(kf, q2[h * 2 + dt], acc, 0, 0, 0);
            }
            sh[knt] = acc;
        }
        // softmax (no max-subtraction; scores bounded)
        const float* bp = attn_bias + (h * 49 + qcl) * 49;
        float e[4][4], sum = 0.f;
        #pragma unroll
        for (int knt = 0; knt < 4; ++knt)
            #pragma unroll
            for (int r = 0; r < 4; ++r) {
                float v = fmaf(sh[knt][r], scale, bp[kcl[knt][r]]);
                e[knt][r] = keep[knt][r] ? __expf(v) : 0.f;
                sum += e[knt][r];
            }
        sum += __shfl_xor(sum, 16);
        sum += __shfl_xor(sum, 32);
        float inv = qo ? __builtin_amdgcn_rcpf(sum) : 0.f;
        half4 p2[4];
        #pragma unroll
        for (int knt = 0; knt < 4; ++knt) {
            half4 pk;
            #pragma unroll
            for (int r = 0; r < 4; ++r) pk[r] = (_Float16)(e[knt][r] * inv);
            p2[knt] = pk;
        }
        // PV: A = V from LDS (cross-token), B = p2 regs
        #pragma unroll
        for (int ntd = 0; ntd < 2; ++ntd) {
            f32x4 acc = {0.f, 0.f, 0.f, 0.f};
            #pragma unroll
            for (int ks = 0; ks < 4; ++ks) {
                half4 va = *(half4*)&R2[(h * 32 + ntd * 16 + l15) * 72 + ks * 16 + l4 * 4];
                acc = MFMA16(va, p2[ks], acc, 0, 0, 0);
            }
            o2[h * 2 + ntd] = pk4(acc);
        }
    }

    // ---- proj (K=16, B = o2 regs) + residual (float4) ---------------------
    size_t tbase;
    {
        int tt = tcol & 63;
        int i = div7d(tt), j = tt - i * 7;
        int row = wh * WS + i + 3; if (row >= HH) row -= HH;
        int col = ww * WS + j + 3; if (col >= HH) col -= HH;
        tbase = ((size_t)b * HW + row * HH + col) * 96;
    }
    float x2v[6][4];
    #pragma unroll
    for (int nt = 0; nt < 6; ++nt) {
        f32x4 acc = {0.f, 0.f, 0.f, 0.f};
        #pragma unroll
        for (int kt = 0; kt < 6; ++kt) {
            half4 a = *(const half4*)&projp[((nt * 6 + kt) * 4 + l4) * 64 + l15 * 4];
            acc = MFMA16(a, o2[kt], acc, 0, 0, 0);
        }
        int n0 = nt * 16 + l4 * 4;
        f32x4 pb4 = *(const f32x4*)&proj_b[n0];
        if (tok_ok) {
            f32x4 xr4 = *(const f32x4*)&x[tbase + n0];
            #pragma unroll
            for (int r = 0; r < 4; ++r)
                x2v[nt][r] = xr4[r] + acc[r] + pb4[r];
        } else {
            #pragma unroll
            for (int r = 0; r < 4; ++r) x2v[nt][r] = 0.f;
        }
    }

    // ---- LN2 in-register (affine folded): reduce over l4 (2 shuffles) -----
    float mu2, rs2;
    {
        float sum = 0.f, sq = 0.f;
        #pragma unroll
        for (int nt = 0; nt < 6; ++nt)
            #pragma unroll
            for (int r = 0; r < 4; ++r) { float v = x2v[nt][r]; sum += v; sq += v * v; }
        sum += __shfl_xor(sum, 16); sq += __shfl_xor(sq, 16);
        sum += __shfl_xor(sum, 32); sq += __shfl_xor(sq, 32);
        mu2 = sum * (1.0f / 96.0f);
        rs2 = rsqrtf(sq * (1.0f / 96.0f) - mu2 * mu2 + 1e-5f);
    }
    half4 xt2[6];
    #pragma unroll
    for (int nt = 0; nt < 6; ++nt) {
        half4 st;
        #pragma unroll
        for (int r = 0; r < 4; ++r)
            st[r] = (_Float16)((x2v[nt][r] - mu2) * rs2);
        xt2[nt] = st;
    }

    // ---- MLP GEMM1 (K=16, B = xt2 regs) + GELU -> yt2 regs ----------------
    half4 yt2[6];
    #pragma unroll
    for (int nt = 0; nt < 6; ++nt) {
        f32x4 acc = {0.f, 0.f, 0.f, 0.f};
        #pragma unroll
        for (int kt = 0; kt < 6; ++kt) {
            half4 a = *(const half4*)&w1p[((nt * 6 + kt) * 4 + l4) * 64 + l15 * 4];
            acc = MFMA16(a, xt2[kt], acc, 0, 0, 0);
        }
        int n0 = nt * 16 + l4 * 4;
        f32x4 b14 = *(const f32x4*)&biasf[288 + n0];
        half4 st;
        #pragma unroll
        for (int r = 0; r < 4; ++r) {
            float v = acc[r] + b14[r];
            // gelu(v) ~= v * sigmoid(v*(1.5957691 + 0.0713548*v^2))
            float v2 = v * v;
            float c2 = fmaf(v2, 0.0713548163f, 1.5957691216f);
            float z  = v * c2;
            float ex = __expf(-z);
            st[r] = (_Float16)(v * __builtin_amdgcn_rcpf(1.0f + ex));
        }
        yt2[nt] = st;
    }

    // ---- MLP GEMM2 (K=16, B = yt2 regs) + final residual -> out -----------
    #pragma unroll
    for (int nt = 0; nt < 6; ++nt) {
        f32x4 acc = {0.f, 0.f, 0.f, 0.f};
        #pragma unroll
        for (int kt = 0; kt < 6; ++kt) {
            half4 a = *(const half4*)&w2p[((nt * 6 + kt) * 4 + l4) * 64 + l15 * 4];
            acc = MFMA16(a, yt2[kt], acc, 0, 0, 0);
        }
        int n0 = nt * 16 + l4 * 4;
        f32x4 b24 = *(const f32x4*)&mlp_b2[n0];
        if (tok_ok) {
            f32x4 o;
            #pragma unroll
            for (int r = 0; r < 4; ++r)
                o[r] = x2v[nt][r] + acc[r] + b24[r];
            *(f32x4*)&out[tbase + n0] = o;
        }
    }
    __builtin_amdgcn_s_setprio(0);
}

extern "C" void kernel_launch(void* const* d_in, const int* in_sizes, int n_in,
                              void* d_out, int out_size, void* d_ws, size_t ws_size,
                              hipStream_t stream) {
    (void)in_sizes; (void)n_in; (void)ws_size; (void)out_size;
    const float* x         = (const float*)d_in[0];
    const float* qkv_w     = (const float*)d_in[1];
    const float* qkv_b     = (const float*)d_in[2];
    const float* attn_bias = (const float*)d_in[3];
    const float* proj_w    = (const float*)d_in[4];
    const float* proj_b    = (const float*)d_in[5];
    const float* ln1_g     = (const float*)d_in[6];
    const float* ln1_b     = (const float*)d_in[7];
    const float* ln2_g     = (const float*)d_in[8];
    const float* ln2_b     = (const float*)d_in[9];
    const float* mlp_w1    = (const float*)d_in[10];
    const float* mlp_b1    = (const float*)d_in[11];
    const float* mlp_w2    = (const float*)d_in[12];
    const float* mlp_b2    = (const float*)d_in[13];
    float* out = (float*)d_out;
    _Float16* wpack = (_Float16*)d_ws;
    float* biasf = (float*)((char*)d_ws + BIASF_BYTE);

    pack_wE<<<218, 256, 0, stream>>>(qkv_w, proj_w, mlp_w1, mlp_w2,
                                     ln1_g, ln1_b, ln2_g, ln2_b,
                                     qkv_b, mlp_b1, wpack, biasf);
    attn_kE<<<64 * 64, 256, 0, stream>>>(x, attn_bias, proj_b, mlp_b2,
                                         wpack, biasf, out);
}

// Round 18
// 131.455 us; speedup vs baseline: 1.6243x; 1.6243x over previous
//
#include <hip/hip_runtime.h>
#include <math.h>

typedef _Float16 half8 __attribute__((ext_vector_type(8)));
typedef _Float16 half4 __attribute__((ext_vector_type(4)));
typedef float f32x4 __attribute__((ext_vector_type(4)));

#define MFMA_F16 __builtin_amdgcn_mfma_f32_16x16x32_f16

constexpr int WS = 7, HH = 56, HW = 3136;

// d_ws layout: fp16 tiles then f32 folded biases
constexpr int QKVP_OFF  = 0;       // 27648 fp16
constexpr int PROJP_OFF = 27648;   // 9216
constexpr int W1P_OFF   = 36864;   // 9216
constexpr int W2P_OFF   = 46080;   // 9216 -> 55296 fp16 = 110592 B
constexpr int BIASF_BYTE = 110592; // f32 [288 qkv' | 96 mlp1'] = 1536 B

__device__ __forceinline__ int labF(int v) { return v < 49 ? 0 : (v < 53 ? 1 : 2); }
__device__ __forceinline__ int div7f(int v) { return (v * 9363) >> 16; }  // valid 0..63

// ---------------------------------------------------------------------------
// Weight pre-pack with LN-affine folding (identical to R14's pack_wC).
// ---------------------------------------------------------------------------
__global__ __launch_bounds__(256) void pack_wF(
    const float* __restrict__ qkv_w, const float* __restrict__ proj_w,
    const float* __restrict__ w1, const float* __restrict__ w2,
    const float* __restrict__ ln1_g, const float* __restrict__ ln1_b,
    const float* __restrict__ ln2_g, const float* __restrict__ ln2_b,
    const float* __restrict__ qkv_b, const float* __restrict__ mlp_b1,
    _Float16* __restrict__ ws, float* __restrict__ bias_out)
{
    int blk = blockIdx.x;
    if (blk < 216) {
        int i = blk * 256 + threadIdx.x;
        const float* src; int ncol, local; const float* gv = nullptr;
        if (i < 27648)      { src = qkv_w;  ncol = 288; local = i; gv = ln1_g; }
        else if (i < 36864) { src = proj_w; ncol = 96;  local = i - 27648; }
        else if (i < 46080) { src = w1;     ncol = 96;  local = i - 36864; gv = ln2_g; }
        else                { src = w2;     ncol = 96;  local = i - 46080; }
        int j = local & 7, col = (local >> 3) & 15, ksub = (local >> 7) & 3;
        int rest = local >> 9;
        int kb = rest % 3, nt = rest / 3;
        int k = kb * 32 + ksub * 8 + j, n = nt * 16 + col;
        float v = src[k * ncol + n];
        if (gv) v *= gv[k];
        ws[i] = (_Float16)v;
    } else if (blk == 216) {
        int n = threadIdx.x;
        float s = qkv_b[n];
        for (int k = 0; k < 96; ++k) s += ln1_b[k] * qkv_w[k * 288 + n];
        bias_out[n] = s;
    } else {
        int t = threadIdx.x;
        if (t < 32) {
            int n = 256 + t;
            float s = qkv_b[n];
            for (int k = 0; k < 96; ++k) s += ln1_b[k] * qkv_w[k * 288 + n];
            bias_out[n] = s;
        } else if (t < 128) {
            int n = t - 32;
            float s = mlp_b1[n];
            for (int k = 0; k < 96; ++k) s += ln2_b[k] * w1[k * 96 + n];
            bias_out[288 + n] = s;
        }
    }
}

// ---------------------------------------------------------------------------
// Fully fused Swin block, transposed GEMMs (D col = token) — R14 structure:
// 2 barriers, wave-3 V-pad zeroing, setprio tail.  New in this round:
// softmax attn_bias loads vectorized (12 VMEM/thread instead of 48).
// LDS planes aliased over time (36.9 KB -> 4 blocks/CU):
//   region A [0,12288):      XLN -> Qu -> Pu(lo) -> Ou -> XT
//   region B [12288,24576):  Ku -> Pu(hi) -> YT
//   region V [24576,36864):  Vu
// ---------------------------------------------------------------------------
__global__ __launch_bounds__(256, 4) void attn_kF(
    const float* __restrict__ x,
    const float* __restrict__ attn_bias,
    const float* __restrict__ proj_b,
    const float* __restrict__ mlp_b2,
    const _Float16* __restrict__ wpack,
    const float* __restrict__ biasf,
    float* __restrict__ out)
{
    __shared__ __align__(16) char smem[36864];

    _Float16*  XLN = (_Float16*)smem;
    _Float16*  Qu  = (_Float16*)smem;
    _Float16*  Ku  = (_Float16*)(smem + 12288);
    _Float16*  Vu  = (_Float16*)(smem + 24576);
    _Float16*  Pu  = (_Float16*)smem;            // 24 planes spanning A+B
    _Float16*  Ou  = (_Float16*)smem;            // planes 0..11
    _Float16*  XT  = (_Float16*)smem;
    _Float16*  YT  = (_Float16*)(smem + 12288);

    const _Float16* qkvp  = wpack + QKVP_OFF;
    const _Float16* projp = wpack + PROJP_OFF;
    const _Float16* w1p   = wpack + W1P_OFF;
    const _Float16* w2p   = wpack + W2P_OFF;

    const int blk = blockIdx.x;
    const int b   = blk >> 6;
    const int w   = blk & 63;
    const int wh  = w >> 3, ww = w & 7;
    const int tid = threadIdx.x;
    const int wv  = tid >> 6, lane = tid & 63;
    const int l15 = lane & 15, l4 = lane >> 4;

    const int  tcol   = wv * 16 + l15;     // this thread's token (D column)
    const bool tok_ok = tcol < 49;

    // ---- wave 3 zeroes V pad planes (tok 48-63) before its own V store ----
    if (wv == 3) {
        uint4* v4 = (uint4*)Vu;
        #pragma unroll
        for (int h = 0; h < 3; ++h)
            v4[(h * 8 + 6) * 32 + lane] = make_uint4(0, 0, 0, 0);
    }

    // ---- gather window (rolled) into registers: 4 threads/token ----------
    const int t_own = tid >> 2, part = tid & 3;
    const bool active = (tid < 196);
    float4 xq[6];
    float m = 0.f, rinv = 0.f;
    if (active) {
        int i = div7f(t_own), j = t_own - i * 7;
        int row = wh * WS + i + 3; if (row >= HH) row -= HH;
        int col = ww * WS + j + 3; if (col >= HH) col -= HH;
        const float* xp = &x[(((size_t)b * HW + row * HH + col) * 96) + part * 24];
        #pragma unroll
        for (int q = 0; q < 6; ++q) xq[q] = *(const float4*)&xp[q * 4];
        float sum = 0.f, sq = 0.f;
        #pragma unroll
        for (int q = 0; q < 6; ++q) {
            sum += xq[q].x + xq[q].y + xq[q].z + xq[q].w;
            sq  += xq[q].x * xq[q].x + xq[q].y * xq[q].y
                 + xq[q].z * xq[q].z + xq[q].w * xq[q].w;
        }
        sum += __shfl_xor(sum, 1); sq += __shfl_xor(sq, 1);
        sum += __shfl_xor(sum, 2); sq += __shfl_xor(sq, 2);
        m = sum * (1.0f / 96.0f);
        rinv = rsqrtf(sq * (1.0f / 96.0f) - m * m + 1e-5f);
    }

    // ---- normalize (affine folded) -> XLN tiles (own-wave rows) -----------
    if (active) {
        #pragma unroll
        for (int cc = 0; cc < 3; ++cc) {
            half8 pk;
            #pragma unroll
            for (int j = 0; j < 8; ++j) {
                float v; int qi = cc * 2 + (j >> 2);
                if ((j & 3) == 0) v = xq[qi].x;
                else if ((j & 3) == 1) v = xq[qi].y;
                else if ((j & 3) == 2) v = xq[qi].z;
                else v = xq[qi].w;
                pk[j] = (_Float16)((v - m) * rinv);
            }
            *(half8*)&XLN[(part * 3 + cc) * 512 + t_own * 8] = pk;
        }
    }
    // NO barrier: B-frag cols below are own-wave tokens.

    // ---- QKV GEMM (transposed: A=W^T, B=XLN) ------------------------------
    {
        half8 bx[3];
        #pragma unroll
        for (int kb = 0; kb < 3; ++kb)
            bx[kb] = *(half8*)&XLN[(kb * 4 + l4) * 512 + tcol * 8];

        // Q: nt 0..5 (unguarded: garbage cols replaced in softmax)
        #pragma unroll
        for (int nt = 0; nt < 6; ++nt) {
            f32x4 acc = {0.f, 0.f, 0.f, 0.f};
            #pragma unroll
            for (int kb = 0; kb < 3; ++kb) {
                half8 bw = *(const half8*)&qkvp[((nt * 3 + kb) * 4 + l4) * 128 + l15 * 8];
                acc = MFMA_F16(bw, bx[kb], acc, 0, 0, 0);
            }
            int n0 = nt * 16 + l4 * 4;
            f32x4 b4 = *(const f32x4*)&biasf[n0];
            int h = n0 >> 5, d0 = n0 & 31;
            half4 st;
            #pragma unroll
            for (int r = 0; r < 4; ++r) st[r] = (_Float16)(acc[r] + b4[r]);
            *(half4*)&Qu[(h * 4 + (d0 >> 3)) * 512 + tcol * 8 + (d0 & 7)] = st;
        }
        // K: nt 6..11
        #pragma unroll
        for (int nt = 6; nt < 12; ++nt) {
            f32x4 acc = {0.f, 0.f, 0.f, 0.f};
            #pragma unroll
            for (int kb = 0; kb < 3; ++kb) {
                half8 bw = *(const half8*)&qkvp[((nt * 3 + kb) * 4 + l4) * 128 + l15 * 8];
                acc = MFMA_F16(bw, bx[kb], acc, 0, 0, 0);
            }
            int n0 = nt * 16 + l4 * 4;
            f32x4 b4 = *(const f32x4*)&biasf[n0];
            int n2 = n0 - 96, h = n2 >> 5, d0 = n2 & 31;
            half4 st;
            #pragma unroll
            for (int r = 0; r < 4; ++r) st[r] = (_Float16)(acc[r] + b4[r]);
            *(half4*)&Ku[(h * 4 + (d0 >> 3)) * 512 + tcol * 8 + (d0 & 7)] = st;
        }
        // V: nt 12..17 (uniform per-thread guard; pad cols stay zero)
        #pragma unroll
        for (int nt = 12; nt < 18; ++nt) {
            f32x4 acc = {0.f, 0.f, 0.f, 0.f};
            #pragma unroll
            for (int kb = 0; kb < 3; ++kb) {
                half8 bw = *(const half8*)&qkvp[((nt * 3 + kb) * 4 + l4) * 128 + l15 * 8];
                acc = MFMA_F16(bw, bx[kb], acc, 0, 0, 0);
            }
            int n0 = nt * 16 + l4 * 4;
            f32x4 b4 = *(const f32x4*)&biasf[n0];
            int n2 = n0 - 192, h = n2 >> 5, d0 = n2 & 31;
            if (tok_ok) {
                int vb = (h * 8 + (tcol >> 3)) * 256 + d0 * 8 + (tcol & 7);
                #pragma unroll
                for (int r = 0; r < 4; ++r)
                    Vu[vb + r * 8] = (_Float16)(acc[r] + b4[r]);
            }
        }
    }
    __syncthreads();   // B2: K/V published for cross-wave reads

    // ---- scores (transposed: A=K, B=Q): D rows=k, col=q=tcol --------------
    f32x4 s[3][4];
    #pragma unroll
    for (int h = 0; h < 3; ++h) {
        half8 qf = *(half8*)&Qu[(h * 4 + l4) * 512 + tcol * 8];
        #pragma unroll
        for (int knt = 0; knt < 4; ++knt) {
            half8 kf = *(half8*)&Ku[(h * 4 + l4) * 512 + (knt * 16 + l15) * 8];
            f32x4 z = {0.f, 0.f, 0.f, 0.f};
            s[h][knt] = MFMA_F16(kf, qf, z, 0, 0, 0);
        }
    }
    __syncthreads();   // B3: Q,K dead for ALL waves -> P may overwrite A+B

    // ---- softmax: q uniform per thread; VECTORIZED bias loads -------------
    {
        const float scale = 0.17677669529663687f;
        const bool qo = tok_ok;
        const int qcl = qo ? tcol : 48;

        // batched bias loads: 9x float4 + 3x scalar (k=48) per thread
        f32x4 bias4[3][3];
        float bias48[3];
        #pragma unroll
        for (int h = 0; h < 3; ++h) {
            const float* bp = attn_bias + (h * 49 + qcl) * 49;
            #pragma unroll
            for (int knt = 0; knt < 3; ++knt)
                bias4[h][knt] = *(const f32x4*)&bp[knt * 16 + l4 * 4];
            bias48[h] = bp[48];
        }

        // mask table (head-independent)
        bool keep[4][4];
        {
            int qi = div7f(qcl), qj = qcl - qi * 7;
            int lqr = labF(wh * WS + qi), lqc = labF(ww * WS + qj);
            #pragma unroll
            for (int knt = 0; knt < 4; ++knt) {
                #pragma unroll
                for (int r = 0; r < 4; ++r) {
                    int k = knt * 16 + l4 * 4 + r;
                    int kc = k < 49 ? k : 48;
                    int ki = div7f(kc), kj = kc - ki * 7;
                    keep[knt][r] = qo && (k < 49) &&
                                   (lqr == labF(wh * WS + ki)) &&
                                   (lqc == labF(ww * WS + kj));
                }
            }
        }

        #pragma unroll
        for (int h = 0; h < 3; ++h) {
            float e[4][4], sum = 0.f;
            #pragma unroll
            for (int knt = 0; knt < 3; ++knt)
                #pragma unroll
                for (int r = 0; r < 4; ++r) {
                    float v = fmaf(s[h][knt][r], scale, bias4[h][knt][r]);
                    e[knt][r] = keep[knt][r] ? __expf(v) : 0.f;
                    sum += e[knt][r];
                }
            // knt=3: only k=48 (l4==0, r==0) can be live
            #pragma unroll
            for (int r = 0; r < 4; ++r) {
                float v = fmaf(s[h][3][r], scale, bias48[h]);
                e[3][r] = keep[3][r] ? __expf(v) : 0.f;
                sum += e[3][r];
            }
            sum += __shfl_xor(sum, 16);
            sum += __shfl_xor(sum, 32);
            float inv = qo ? __builtin_amdgcn_rcpf(sum) : 0.f;
            #pragma unroll
            for (int knt = 0; knt < 4; ++knt) {
                int k0 = knt * 16 + l4 * 4;
                half4 pk;
                #pragma unroll
                for (int r = 0; r < 4; ++r) pk[r] = (_Float16)(e[knt][r] * inv);
                *(half4*)&Pu[(h * 8 + (k0 >> 3)) * 512 + tcol * 8 + (k0 & 7)] = pk;
            }
        }
    }
    // Below: wave-private own-token rows/cols or read-only V; no barriers.
    __builtin_amdgcn_s_setprio(1);

    // ---- PV (transposed: A=V^T, B=P^T): D rows=d, col=q=tcol --------------
    #pragma unroll
    for (int h = 0; h < 3; ++h) {
        half8 pb0 = *(half8*)&Pu[(h * 8 + 0 + l4) * 512 + tcol * 8];
        half8 pb1 = *(half8*)&Pu[(h * 8 + 4 + l4) * 512 + tcol * 8];
        #pragma unroll
        for (int ntd = 0; ntd < 2; ++ntd) {
            f32x4 acc = {0.f, 0.f, 0.f, 0.f};
            half8 va0 = *(half8*)&Vu[(h * 8 + 0 + l4) * 256 + (ntd * 16 + l15) * 8];
            acc = MFMA_F16(va0, pb0, acc, 0, 0, 0);
            half8 va1 = *(half8*)&Vu[(h * 8 + 4 + l4) * 256 + (ntd * 16 + l15) * 8];
            acc = MFMA_F16(va1, pb1, acc, 0, 0, 0);
            int c0 = h * 32 + ntd * 16 + l4 * 4;
            half4 st;
            #pragma unroll
            for (int r = 0; r < 4; ++r) st[r] = (_Float16)acc[r];
            *(half4*)&Ou[(c0 >> 3) * 512 + tcol * 8 + (c0 & 7)] = st;
        }
    }

    // ---- proj (transposed) + residual (float4) -> registers ---------------
    size_t tbase;
    {
        int tt = tcol & 63;
        int i = div7f(tt), j = tt - i * 7;
        int row = wh * WS + i + 3; if (row >= HH) row -= HH;
        int col = ww * WS + j + 3; if (col >= HH) col -= HH;
        tbase = ((size_t)b * HW + row * HH + col) * 96;
    }
    float x2v[6][4];
    {
        half8 ob[3];
        #pragma unroll
        for (int kb = 0; kb < 3; ++kb)
            ob[kb] = *(half8*)&Ou[(kb * 4 + l4) * 512 + tcol * 8];
        #pragma unroll
        for (int nt = 0; nt < 6; ++nt) {
            f32x4 acc = {0.f, 0.f, 0.f, 0.f};
            #pragma unroll
            for (int kb = 0; kb < 3; ++kb) {
                half8 bw = *(const half8*)&projp[((nt * 3 + kb) * 4 + l4) * 128 + l15 * 8];
                acc = MFMA_F16(bw, ob[kb], acc, 0, 0, 0);
            }
            int n0 = nt * 16 + l4 * 4;
            f32x4 pb4 = *(const f32x4*)&proj_b[n0];
            if (tok_ok) {
                f32x4 xr4 = *(const f32x4*)&x[tbase + n0];
                #pragma unroll
                for (int r = 0; r < 4; ++r)
                    x2v[nt][r] = xr4[r] + acc[r] + pb4[r];
            } else {
                #pragma unroll
                for (int r = 0; r < 4; ++r) x2v[nt][r] = 0.f;
            }
        }
    }

    // ---- LN2 in-register: one token/thread; reduce over l4 (2 shuffles) ---
    float mu2, rs2;
    {
        float sum = 0.f, sq = 0.f;
        #pragma unroll
        for (int nt = 0; nt < 6; ++nt)
            #pragma unroll
            for (int r = 0; r < 4; ++r) { float v = x2v[nt][r]; sum += v; sq += v * v; }
        sum += __shfl_xor(sum, 16); sq += __shfl_xor(sq, 16);
        sum += __shfl_xor(sum, 32); sq += __shfl_xor(sq, 32);
        mu2 = sum * (1.0f / 96.0f);
        rs2 = rsqrtf(sq * (1.0f / 96.0f) - mu2 * mu2 + 1e-5f);
    }

    // ---- x^ -> XT tiles (b64, own token rows; over Ou after ob read) ------
    #pragma unroll
    for (int nt = 0; nt < 6; ++nt) {
        int n0 = nt * 16 + l4 * 4;
        half4 st;
        #pragma unroll
        for (int r = 0; r < 4; ++r)
            st[r] = (_Float16)((x2v[nt][r] - mu2) * rs2);
        *(half4*)&XT[(n0 >> 3) * 512 + tcol * 8 + (n0 & 7)] = st;
    }

    // ---- MLP GEMM1 (transposed) + GELU -> YT tiles ------------------------
    {
        half8 xb[3];
        #pragma unroll
        for (int kb = 0; kb < 3; ++kb)
            xb[kb] = *(half8*)&XT[(kb * 4 + l4) * 512 + tcol * 8];
        #pragma unroll
        for (int nt = 0; nt < 6; ++nt) {
            f32x4 acc = {0.f, 0.f, 0.f, 0.f};
            #pragma unroll
            for (int kb = 0; kb < 3; ++kb) {
                half8 bw = *(const half8*)&w1p[((nt * 3 + kb) * 4 + l4) * 128 + l15 * 8];
                acc = MFMA_F16(bw, xb[kb], acc, 0, 0, 0);
            }
            int n0 = nt * 16 + l4 * 4;
            f32x4 b14 = *(const f32x4*)&biasf[288 + n0];
            half4 st;
            #pragma unroll
            for (int r = 0; r < 4; ++r) {
                float v = acc[r] + b14[r];
                // gelu(v) ~= v * sigmoid(v*(1.5957691 + 0.0713548*v^2))
                float v2 = v * v;
                float c2 = fmaf(v2, 0.0713548163f, 1.5957691216f);
                float z  = v * c2;
                float ex = __expf(-z);
                st[r] = (_Float16)(v * __builtin_amdgcn_rcpf(1.0f + ex));
            }
            *(half4*)&YT[(n0 >> 3) * 512 + tcol * 8 + (n0 & 7)] = st;
        }
    }

    // ---- MLP GEMM2 (transposed) + final residual -> out (float4) ----------
    {
        half8 yb[3];
        #pragma unroll
        for (int kb = 0; kb < 3; ++kb)
            yb[kb] = *(half8*)&YT[(kb * 4 + l4) * 512 + tcol * 8];
        #pragma unroll
        for (int nt = 0; nt < 6; ++nt) {
            f32x4 acc = {0.f, 0.f, 0.f, 0.f};
            #pragma unroll
            for (int kb = 0; kb < 3; ++kb) {
                half8 bw = *(const half8*)&w2p[((nt * 3 + kb) * 4 + l4) * 128 + l15 * 8];
                acc = MFMA_F16(bw, yb[kb], acc, 0, 0, 0);
            }
            int n0 = nt * 16 + l4 * 4;
            f32x4 b24 = *(const f32x4*)&mlp_b2[n0];
            if (tok_ok) {
                f32x4 o;
                #pragma unroll
                for (int r = 0; r < 4; ++r)
                    o[r] = x2v[nt][r] + acc[r] + b24[r];
                *(f32x4*)&out[tbase + n0] = o;
            }
        }
    }
    __builtin_amdgcn_s_setprio(0);
}

extern "C" void kernel_launch(void* const* d_in, const int* in_sizes, int n_in,
                              void* d_out, int out_size, void* d_ws, size_t ws_size,
                              hipStream_t stream) {
    (void)in_sizes; (void)n_in; (void)ws_size; (void)out_size;
    const float* x         = (const float*)d_in[0];
    const float* qkv_w     = (const float*)d_in[1];
    const float* qkv_b     = (const float*)d_in[2];
    const float* attn_bias = (const float*)d_in[3];
    const float* proj_w    = (const float*)d_in[4];
    const float* proj_b    = (const float*)d_in[5];
    const float* ln1_g     = (const float*)d_in[6];
    const float* ln1_b     = (const float*)d_in[7];
    const float* ln2_g     = (const float*)d_in[8];
    const float* ln2_b     = (const float*)d_in[9];
    const float* mlp_w1    = (const float*)d_in[10];
    const float* mlp_b1    = (const float*)d_in[11];
    const float* mlp_w2    = (const float*)d_in[12];
    const float* mlp_b2    = (const float*)d_in[13];
    float* out = (float*)d_out;
    _Float16* wpack = (_Float16*)d_ws;
    float* biasf = (float*)((char*)d_ws + BIASF_BYTE);

    pack_wF<<<218, 256, 0, stream>>>(qkv_w, proj_w, mlp_w1, mlp_w2,
                                     ln1_g, ln1_b, ln2_g, ln2_b,
                                     qkv_b, mlp_b1, wpack, biasf);
    attn_kF<<<64 * 64, 256, 0, stream>>>(x, attn_bias, proj_b, mlp_b2,
                                         wpack, biasf, out);
}